// Round 2
// baseline (746.025 us; speedup 1.0000x reference)
//
#include <hip/hip_runtime.h>
#include <hip/hip_bf16.h>

// MoE (Gemma 8-expert top-2) sparse bf16 MFMA implementation with runtime
// input-dtype detection (fp32 vs bf16). Pipeline:
//   detect -> zero out -> routing -> weight transposes (K-major bf16) ->
//   x canonicalize (bf16) -> grouped gate/up GEMM (fused gelu*up) ->
//   grouped down GEMM (routing-weight scale + scatter-add atomics).

typedef __attribute__((ext_vector_type(8))) short bf16x8;
typedef __attribute__((ext_vector_type(4))) float f32x4;

#define AS1 __attribute__((address_space(1)))
#define AS3 __attribute__((address_space(3)))

static constexpr int T_TOK = 8192;
static constexpr int HID   = 2048;
static constexpr int INTER = 1024;
static constexpr int NEXP  = 8;
static constexpr int NPAIR = T_TOK * 2;            // 16384 (token, slot) pairs
static constexpr int TM    = 128;                  // row tile (pairs)
static constexpr int BK    = 32;                   // K chunk
static constexpr int MAX_ROWS = NPAIR + NEXP * TM; // 17408 padded rows max
static constexpr int MAX_RT   = MAX_ROWS / TM;     // 136 row tiles max
static constexpr int NT_A = INTER / TM;            // 8 n-tiles (gate/up)
static constexpr int NT_B = HID / TM;              // 16 n-tiles (down)
static constexpr int OUTN = T_TOK * HID;           // 16,777,216 out elements

__device__ __forceinline__ unsigned short f2bf(float f) {
  unsigned u = __float_as_uint(f);
  u += 0x7fffu + ((u >> 16) & 1u);   // RNE
  return (unsigned short)(u >> 16);
}
__device__ __forceinline__ float bf2f(unsigned short h) {
  return __uint_as_float(((unsigned)h) << 16);
}
__device__ __forceinline__ void glds16(const void* g, void* l) {
  __builtin_amdgcn_global_load_lds((const AS1 void*)g, (AS3 void*)l, 16, 0, 0);
}

// ----------------------------------------------------------- dtype detect ---
// flag=1: inputs are bf16. flag=0: inputs are fp32.
// Low 16 bits of each u32 word of x: bf16 data -> a N(0,1) sample (sane
// exponent ~100%); fp32 data -> low mantissa bits (~12.5% sane).
__global__ void detect_k(const unsigned* __restrict__ xw, int* __restrict__ flagp) {
  int tid = threadIdx.x;   // 64 threads
  int cnt = 0;
  for (int i = tid; i < 256; i += 64) {
    unsigned e = (xw[i] >> 7) & 0xffu;   // exponent of low-half bf16
    cnt += (e >= 0x70u && e <= 0x8fu) ? 1 : 0;
  }
  for (int off = 32; off; off >>= 1) cnt += __shfl_down(cnt, off);
  if (tid == 0) *flagp = (cnt >= 192) ? 1 : 0;
}

// -------------------------------------------------------------- zero out ----
__global__ void zero_out_k(unsigned* __restrict__ out, const int* __restrict__ flagp) {
  int n = (*flagp) ? (OUTN / 2) : OUTN;   // u32 words: bf16 out 32MB, fp32 64MB
  int i = blockIdx.x * 256 + threadIdx.x;
  int stride = gridDim.x * 256;
  for (; i < n; i += stride) out[i] = 0u;
}

// ---------------------------------------------------------------- routing ---
__global__ void routing_k(const int* __restrict__ sel, const void* __restrict__ rwv,
                          int* __restrict__ rows, float* __restrict__ wgt,
                          int* __restrict__ offs, const int* __restrict__ flagp) {
  __shared__ int cnt[NEXP], cur[NEXP], offs_s[NEXP + 1];
  int flag = *flagp;
  const unsigned short* rw16 = (const unsigned short*)rwv;
  const float* rwf = (const float*)rwv;
  int tid = threadIdx.x;
  if (tid < NEXP) cnt[tid] = 0;
  __syncthreads();
  for (int p = tid; p < NPAIR; p += 256) atomicAdd(&cnt[sel[p]], 1);
  __syncthreads();
  if (tid == 0) {
    int off = 0;
    for (int e = 0; e < NEXP; ++e) {
      offs_s[e] = off; cur[e] = off;
      off += (cnt[e] + TM - 1) / TM * TM;   // pad each expert to TM rows
    }
    offs_s[NEXP] = off;
  }
  __syncthreads();
  if (tid <= NEXP) offs[tid] = offs_s[tid];
  for (int p = tid; p < NPAIR; p += 256) {
    int e = sel[p];
    int pos = atomicAdd(&cur[e], 1);
    rows[pos] = p >> 1;                                 // token index
    wgt[pos] = flag ? bf2f(rw16[p]) : rwf[p];           // routing weight
  }
  for (int e = 0; e < NEXP; ++e)
    for (int r = offs_s[e] + cnt[e] + tid; r < offs_s[e + 1]; r += 256) {
      rows[r] = 0; wgt[r] = 0.f;   // padding rows: token 0, weight 0
    }
}

// --------------------------------------------------------- x canonicalize ---
__global__ void convert_x_k(const void* __restrict__ xin,
                            unsigned short* __restrict__ xc,
                            const int* __restrict__ flagp) {
  int flag = *flagp;
  const int nvec = (T_TOK * HID) / 8;   // 8 elements per iter
  int v = blockIdx.x * 256 + threadIdx.x;
  int stride = gridDim.x * 256;
  for (; v < nvec; v += stride) {
    if (flag) {
      ((uint4*)xc)[v] = ((const uint4*)xin)[v];
    } else {
      const float4* s = (const float4*)xin;
      float4 a = s[2 * v], b = s[2 * v + 1];
      uint4 o;
      o.x = (unsigned)f2bf(a.x) | ((unsigned)f2bf(a.y) << 16);
      o.y = (unsigned)f2bf(a.z) | ((unsigned)f2bf(a.w) << 16);
      o.z = (unsigned)f2bf(b.x) | ((unsigned)f2bf(b.y) << 16);
      o.w = (unsigned)f2bf(b.z) | ((unsigned)f2bf(b.w) << 16);
      ((uint4*)xc)[v] = o;
    }
  }
}

// -------------------------------------------------------------- transpose ---
// in: [E][R][C] (fp32 or bf16) -> out: [E][C][R] bf16, 64x64 tiles.
__global__ void transpose_k(const void* __restrict__ in,
                            unsigned short* __restrict__ out, int R, int C,
                            const int* __restrict__ flagp) {
  __shared__ unsigned short tile[64][65];
  int flag = *flagp;
  int e = blockIdx.z;
  int c0 = blockIdx.x * 64, r0 = blockIdx.y * 64;
  int tx = threadIdx.x & 31, ty = threadIdx.x >> 5;
  if (flag) {
    const unsigned short* src = (const unsigned short*)in + (size_t)e * R * C;
#pragma unroll
    for (int i = 0; i < 8; ++i) {
      int rr = ty + i * 8;
      ushort2 v = *(const ushort2*)(src + (size_t)(r0 + rr) * C + c0 + tx * 2);
      tile[rr][tx * 2] = v.x;
      tile[rr][tx * 2 + 1] = v.y;
    }
  } else {
    const float* src = (const float*)in + (size_t)e * R * C;
#pragma unroll
    for (int i = 0; i < 8; ++i) {
      int rr = ty + i * 8;
      float2 v = *(const float2*)(src + (size_t)(r0 + rr) * C + c0 + tx * 2);
      tile[rr][tx * 2] = f2bf(v.x);
      tile[rr][tx * 2 + 1] = f2bf(v.y);
    }
  }
  __syncthreads();
  unsigned short* dst = out + (size_t)e * R * C;
#pragma unroll
  for (int i = 0; i < 8; ++i) {
    int cc = ty + i * 8;
    ushort2 v;
    v.x = tile[tx * 2][cc];
    v.y = tile[tx * 2 + 1][cc];
    *(ushort2*)(dst + (size_t)(c0 + cc) * R + r0 + tx * 2) = v;
  }
}

// ------------------------------------------------------ gate/up fused GEMM ---
// act[r][i] = gelu_tanh(xc[rows[r]] . gwT[e][i]) * (xc[rows[r]] . uwT[e][i])
__global__ __launch_bounds__(256, 2) void gemm_gateup(
    const unsigned short* __restrict__ xc,    // [T][HID] bf16
    const unsigned short* __restrict__ gwT,   // [E][INTER][HID] bf16
    const unsigned short* __restrict__ uwT,   // [E][INTER][HID] bf16
    const int* __restrict__ rows, const int* __restrict__ offs,
    unsigned short* __restrict__ act) {
  int nRT = offs[NEXP] >> 7;
  int rowTile = blockIdx.x >> 3;
  if (rowTile >= nRT) return;
  int nt = blockIdx.x & 7;
  int row0 = rowTile << 7;
  int e = 0;
  while (row0 >= offs[e + 1]) ++e;

  __shared__ __align__(16) unsigned short xs[TM * BK];  // [m][k]
  __shared__ __align__(16) unsigned short gs[TM * BK];  // [n][k]
  __shared__ __align__(16) unsigned short us[TM * BK];  // [n][k]

  int tid = threadIdx.x;
  int wave = tid >> 6, lane = tid & 63;
  int lrow = lane & 15, lquad = lane >> 4;
  int wm = (wave >> 1) << 6, wn = (wave & 1) << 6;

  int mslot = tid >> 2;            // LDS row this lane stages
  int kk = (tid & 3) << 3;         // k offset within row (8 shorts)
  int xb0 = rows[row0 + mslot] * HID + kk;
  int xb1 = rows[row0 + 64 + mslot] * HID + kk;
  const unsigned short* gB = gwT + ((size_t)e * INTER + (size_t)nt * TM) * HID;
  const unsigned short* uB = uwT + ((size_t)e * INTER + (size_t)nt * TM) * HID;
  size_t wb0 = (size_t)mslot * HID + kk;
  size_t wb1 = (size_t)(64 + mslot) * HID + kk;
  int lds0 = (wave * 64) * 8;      // wave-uniform LDS base (shorts)
  int lds1 = (256 + wave * 64) * 8;

  f32x4 accg[4][4] = {};
  f32x4 accu[4][4] = {};

  for (int k0 = 0; k0 < HID; k0 += BK) {
    glds16(xc + xb0 + k0, xs + lds0);
    glds16(xc + xb1 + k0, xs + lds1);
    glds16(gB + wb0 + k0, gs + lds0);
    glds16(gB + wb1 + k0, gs + lds1);
    glds16(uB + wb0 + k0, us + lds0);
    glds16(uB + wb1 + k0, us + lds1);
    __syncthreads();
    bf16x8 bg[4], bu[4];
#pragma unroll
    for (int j = 0; j < 4; ++j) {
      int n = wn + j * 16 + lrow;
      bg[j] = *(const bf16x8*)(gs + n * BK + lquad * 8);
      bu[j] = *(const bf16x8*)(us + n * BK + lquad * 8);
    }
#pragma unroll
    for (int i = 0; i < 4; ++i) {
      int m = wm + i * 16 + lrow;
      bf16x8 af = *(const bf16x8*)(xs + m * BK + lquad * 8);
#pragma unroll
      for (int j = 0; j < 4; ++j) {
        accg[i][j] = __builtin_amdgcn_mfma_f32_16x16x32_bf16(af, bg[j], accg[i][j], 0, 0, 0);
        accu[i][j] = __builtin_amdgcn_mfma_f32_16x16x32_bf16(af, bu[j], accu[i][j], 0, 0, 0);
      }
    }
    __syncthreads();
  }

  int n0 = nt * TM;
#pragma unroll
  for (int i = 0; i < 4; ++i) {
#pragma unroll
    for (int r = 0; r < 4; ++r) {
      int m = row0 + wm + i * 16 + lquad * 4 + r;
      size_t base = (size_t)m * INTER + n0 + wn;
#pragma unroll
      for (int j = 0; j < 4; ++j) {
        float g = accg[i][j][r], u = accu[i][j][r];
        float t = tanhf(0.7978845608f * (g + 0.044715f * g * g * g));
        float a = 0.5f * g * (1.f + t) * u;
        act[base + j * 16 + lrow] = f2bf(a);
      }
    }
  }
}

// ------------------------------------------------- down GEMM + scatter-add ---
__global__ __launch_bounds__(256, 2) void gemm_down(
    const unsigned short* __restrict__ act,   // [rows][INTER] bf16
    const unsigned short* __restrict__ dwT,   // [E][HID][INTER] bf16
    const int* __restrict__ rows, const float* __restrict__ wgt,
    const int* __restrict__ offs, void* __restrict__ outv,
    const int* __restrict__ flagp) {
  int nRT = offs[NEXP] >> 7;
  int rowTile = blockIdx.x >> 4;
  if (rowTile >= nRT) return;
  int flag = *flagp;
  int nt = blockIdx.x & 15;
  int row0 = rowTile << 7;
  int e = 0;
  while (row0 >= offs[e + 1]) ++e;

  __shared__ __align__(16) unsigned short as_[TM * BK];
  __shared__ __align__(16) unsigned short bs[TM * BK];

  int tid = threadIdx.x;
  int wave = tid >> 6, lane = tid & 63;
  int lrow = lane & 15, lquad = lane >> 4;
  int wm = (wave >> 1) << 6, wn = (wave & 1) << 6;

  int mslot = tid >> 2;
  int kk = (tid & 3) << 3;
  size_t ab0 = (size_t)(row0 + mslot) * INTER + kk;
  size_t ab1 = (size_t)(row0 + 64 + mslot) * INTER + kk;
  const unsigned short* dB = dwT + ((size_t)e * HID + (size_t)nt * TM) * INTER;
  size_t wb0 = (size_t)mslot * INTER + kk;
  size_t wb1 = (size_t)(64 + mslot) * INTER + kk;
  int lds0 = (wave * 64) * 8;
  int lds1 = (256 + wave * 64) * 8;

  f32x4 acc[4][4] = {};

  for (int k0 = 0; k0 < INTER; k0 += BK) {
    glds16(act + ab0 + k0, as_ + lds0);
    glds16(act + ab1 + k0, as_ + lds1);
    glds16(dB + wb0 + k0, bs + lds0);
    glds16(dB + wb1 + k0, bs + lds1);
    __syncthreads();
    bf16x8 bf[4];
#pragma unroll
    for (int j = 0; j < 4; ++j)
      bf[j] = *(const bf16x8*)(bs + (wn + j * 16 + lrow) * BK + lquad * 8);
#pragma unroll
    for (int i = 0; i < 4; ++i) {
      bf16x8 af = *(const bf16x8*)(as_ + (wm + i * 16 + lrow) * BK + lquad * 8);
#pragma unroll
      for (int j = 0; j < 4; ++j)
        acc[i][j] = __builtin_amdgcn_mfma_f32_16x16x32_bf16(af, bf[j], acc[i][j], 0, 0, 0);
    }
    __syncthreads();
  }

  int n0 = nt * TM;
#pragma unroll
  for (int i = 0; i < 4; ++i) {
#pragma unroll
    for (int r = 0; r < 4; ++r) {
      int mi = row0 + wm + i * 16 + lquad * 4 + r;
      float w = wgt[mi];
      int token = rows[mi];
      size_t base = (size_t)token * HID + n0 + wn;
      if (flag) {
        // bf16 output: pack (even,odd) column pair, CAS accumulate
#pragma unroll
        for (int j = 0; j < 4; ++j) {
          float v = acc[i][j][r] * w;
          float o = __shfl_xor(v, 1);   // partner column (col^1)
          if (((lrow & 1) == 0) && w != 0.f) {
            unsigned* p = (unsigned*)((unsigned short*)outv + base + j * 16 + lrow);
            unsigned old = __atomic_load_n(p, __ATOMIC_RELAXED), assumed;
            do {
              assumed = old;
              float flo = bf2f((unsigned short)(assumed & 0xffffu));
              float fhi = bf2f((unsigned short)(assumed >> 16));
              unsigned nw = (unsigned)f2bf(flo + v) | ((unsigned)f2bf(fhi + o) << 16);
              old = atomicCAS(p, assumed, nw);
            } while (old != assumed);
          }
        }
      } else {
        // fp32 output: one atomicAdd per lane-column
        if (w != 0.f) {
          float* outf = (float*)outv;
#pragma unroll
          for (int j = 0; j < 4; ++j)
            atomicAdd(outf + base + j * 16 + lrow, acc[i][j][r] * w);
        }
      }
    }
  }
}

// ------------------------------------------------------------------ launch ---
extern "C" void kernel_launch(void* const* d_in, const int* in_sizes, int n_in,
                              void* d_out, int out_size, void* d_ws, size_t ws_size,
                              hipStream_t stream) {
  (void)in_sizes; (void)n_in; (void)out_size; (void)ws_size;
  const void* x   = d_in[0];
  const int* sel  = (const int*)d_in[1];
  const void* rw  = d_in[2];
  const void* gw  = d_in[3];
  const void* uw  = d_in[4];
  const void* dw  = d_in[5];

  char* ws = (char*)d_ws;
  int* offs  = (int*)ws;                     // ints 0..8
  int* flagp = (int*)(ws + 64);              // dtype flag
  int* rows  = (int*)(ws + 256);             // 17408 ints
  float* wgt = (float*)(ws + 256 + MAX_ROWS * 4);
  unsigned short* gwT = (unsigned short*)(ws + 256 + MAX_ROWS * 8);
  unsigned short* uwT = gwT + (size_t)NEXP * HID * INTER;
  unsigned short* dwT = uwT + (size_t)NEXP * HID * INTER;
  unsigned short* xc  = dwT + (size_t)NEXP * HID * INTER;  // [T][HID] bf16
  unsigned short* act = xc + (size_t)T_TOK * HID;          // [17408][1024] bf16

  detect_k<<<1, 64, 0, stream>>>((const unsigned*)x, flagp);
  zero_out_k<<<4096, 256, 0, stream>>>((unsigned*)d_out, flagp);
  routing_k<<<1, 256, 0, stream>>>(sel, rw, rows, wgt, offs, flagp);
  transpose_k<<<dim3(INTER / 64, HID / 64, NEXP), 256, 0, stream>>>(gw, gwT, HID, INTER, flagp);
  transpose_k<<<dim3(INTER / 64, HID / 64, NEXP), 256, 0, stream>>>(uw, uwT, HID, INTER, flagp);
  transpose_k<<<dim3(HID / 64, INTER / 64, NEXP), 256, 0, stream>>>(dw, dwT, INTER, HID, flagp);
  convert_x_k<<<4096, 256, 0, stream>>>(x, xc, flagp);
  gemm_gateup<<<MAX_RT * NT_A, 256, 0, stream>>>(xc, gwT, uwT, rows, offs, act);
  gemm_down<<<MAX_RT * NT_B, 256, 0, stream>>>(act, dwT, rows, wgt, offs, d_out, flagp);
}

// Round 3
// 736.081 us; speedup vs baseline: 1.0135x; 1.0135x over previous
//
#include <hip/hip_runtime.h>
#include <hip/hip_bf16.h>

// MoE (Gemma 8-expert top-2) sparse bf16 MFMA implementation with runtime
// input-dtype detection (fp32 vs bf16). Pipeline:
//   detect -> zero out -> routing -> weight transposes (K-major bf16) ->
//   x canonicalize (bf16) -> grouped gate/up GEMM (fused gelu*up) ->
//   grouped down GEMM (routing-weight scale + scatter-add atomics).
// R3: BK=64 (full 128B lines per staged row, half the barrier drains),
//     launch_bounds(256,3) on gemm_down, sigmoid-form gelu, float4 transposes.

typedef __attribute__((ext_vector_type(8))) short bf16x8;
typedef __attribute__((ext_vector_type(4))) float f32x4;

#define AS1 __attribute__((address_space(1)))
#define AS3 __attribute__((address_space(3)))

static constexpr int T_TOK = 8192;
static constexpr int HID   = 2048;
static constexpr int INTER = 1024;
static constexpr int NEXP  = 8;
static constexpr int NPAIR = T_TOK * 2;            // 16384 (token, slot) pairs
static constexpr int TM    = 128;                  // row tile (pairs)
static constexpr int BK    = 64;                   // K chunk (128B rows)
static constexpr int MAX_ROWS = NPAIR + NEXP * TM; // 17408 padded rows max
static constexpr int MAX_RT   = MAX_ROWS / TM;     // 136 row tiles max
static constexpr int NT_A = INTER / TM;            // 8 n-tiles (gate/up)
static constexpr int NT_B = HID / TM;              // 16 n-tiles (down)
static constexpr int OUTN = T_TOK * HID;           // 16,777,216 out elements

__device__ __forceinline__ unsigned short f2bf(float f) {
  unsigned u = __float_as_uint(f);
  u += 0x7fffu + ((u >> 16) & 1u);   // RNE
  return (unsigned short)(u >> 16);
}
__device__ __forceinline__ float bf2f(unsigned short h) {
  return __uint_as_float(((unsigned)h) << 16);
}
__device__ __forceinline__ void glds16(const void* g, void* l) {
  __builtin_amdgcn_global_load_lds((const AS1 void*)g, (AS3 void*)l, 16, 0, 0);
}

// ----------------------------------------------------------- dtype detect ---
// flag=1: inputs are bf16. flag=0: inputs are fp32.
__global__ void detect_k(const unsigned* __restrict__ xw, int* __restrict__ flagp) {
  int tid = threadIdx.x;   // 64 threads
  int cnt = 0;
  for (int i = tid; i < 256; i += 64) {
    unsigned e = (xw[i] >> 7) & 0xffu;   // exponent of low-half bf16
    cnt += (e >= 0x70u && e <= 0x8fu) ? 1 : 0;
  }
  for (int off = 32; off; off >>= 1) cnt += __shfl_down(cnt, off);
  if (tid == 0) *flagp = (cnt >= 192) ? 1 : 0;
}

// -------------------------------------------------------------- zero out ----
__global__ void zero_out_k(unsigned* __restrict__ out, const int* __restrict__ flagp) {
  int n = (*flagp) ? (OUTN / 2) : OUTN;   // u32 words
  int i = blockIdx.x * 256 + threadIdx.x;
  int stride = gridDim.x * 256;
  for (; i < n; i += stride) out[i] = 0u;
}

// ---------------------------------------------------------------- routing ---
__global__ void routing_k(const int* __restrict__ sel, const void* __restrict__ rwv,
                          int* __restrict__ rows, float* __restrict__ wgt,
                          int* __restrict__ offs, const int* __restrict__ flagp) {
  __shared__ int cnt[NEXP], cur[NEXP], offs_s[NEXP + 1];
  int flag = *flagp;
  const unsigned short* rw16 = (const unsigned short*)rwv;
  const float* rwf = (const float*)rwv;
  int tid = threadIdx.x;
  if (tid < NEXP) cnt[tid] = 0;
  __syncthreads();
  for (int p = tid; p < NPAIR; p += 256) atomicAdd(&cnt[sel[p]], 1);
  __syncthreads();
  if (tid == 0) {
    int off = 0;
    for (int e = 0; e < NEXP; ++e) {
      offs_s[e] = off; cur[e] = off;
      off += (cnt[e] + TM - 1) / TM * TM;   // pad each expert to TM rows
    }
    offs_s[NEXP] = off;
  }
  __syncthreads();
  if (tid <= NEXP) offs[tid] = offs_s[tid];
  for (int p = tid; p < NPAIR; p += 256) {
    int e = sel[p];
    int pos = atomicAdd(&cur[e], 1);
    rows[pos] = p >> 1;                                 // token index
    wgt[pos] = flag ? bf2f(rw16[p]) : rwf[p];           // routing weight
  }
  for (int e = 0; e < NEXP; ++e)
    for (int r = offs_s[e] + cnt[e] + tid; r < offs_s[e + 1]; r += 256) {
      rows[r] = 0; wgt[r] = 0.f;   // padding rows: token 0, weight 0
    }
}

// --------------------------------------------------------- x canonicalize ---
__global__ void convert_x_k(const void* __restrict__ xin,
                            unsigned short* __restrict__ xc,
                            const int* __restrict__ flagp) {
  int flag = *flagp;
  const int nvec = (T_TOK * HID) / 8;   // 8 elements per iter
  int v = blockIdx.x * 256 + threadIdx.x;
  int stride = gridDim.x * 256;
  for (; v < nvec; v += stride) {
    if (flag) {
      ((uint4*)xc)[v] = ((const uint4*)xin)[v];
    } else {
      const float4* s = (const float4*)xin;
      float4 a = s[2 * v], b = s[2 * v + 1];
      uint4 o;
      o.x = (unsigned)f2bf(a.x) | ((unsigned)f2bf(a.y) << 16);
      o.y = (unsigned)f2bf(a.z) | ((unsigned)f2bf(a.w) << 16);
      o.z = (unsigned)f2bf(b.x) | ((unsigned)f2bf(b.y) << 16);
      o.w = (unsigned)f2bf(b.z) | ((unsigned)f2bf(b.w) << 16);
      ((uint4*)xc)[v] = o;
    }
  }
}

// -------------------------------------------------------------- transpose ---
// in: [E][R][C] (fp32 or bf16) -> out: [E][C][R] bf16, 64x64 tiles.
__global__ void transpose_k(const void* __restrict__ in,
                            unsigned short* __restrict__ out, int R, int C,
                            const int* __restrict__ flagp) {
  __shared__ unsigned short tile[64][65];
  int flag = *flagp;
  int e = blockIdx.z;
  int c0 = blockIdx.x * 64, r0 = blockIdx.y * 64;
  int tid = threadIdx.x;
  if (flag) {
    const unsigned short* src = (const unsigned short*)in + (size_t)e * R * C;
    int tx = tid & 7, ty = tid >> 3;   // 8 col-groups x 32 rows
#pragma unroll
    for (int i = 0; i < 2; ++i) {
      int rr = ty + i * 32;
      uint4 v = *(const uint4*)(src + (size_t)(r0 + rr) * C + c0 + tx * 8);
      unsigned short* t = &tile[rr][tx * 8];
      t[0] = (unsigned short)v.x; t[1] = (unsigned short)(v.x >> 16);
      t[2] = (unsigned short)v.y; t[3] = (unsigned short)(v.y >> 16);
      t[4] = (unsigned short)v.z; t[5] = (unsigned short)(v.z >> 16);
      t[6] = (unsigned short)v.w; t[7] = (unsigned short)(v.w >> 16);
    }
  } else {
    const float* src = (const float*)in + (size_t)e * R * C;
    int tx = tid & 15, ty = tid >> 4;  // 16 col-groups x 16 rows
#pragma unroll
    for (int i = 0; i < 4; ++i) {
      int rr = ty + i * 16;
      float4 v = *(const float4*)(src + (size_t)(r0 + rr) * C + c0 + tx * 4);
      unsigned short* t = &tile[rr][tx * 4];
      t[0] = f2bf(v.x); t[1] = f2bf(v.y); t[2] = f2bf(v.z); t[3] = f2bf(v.w);
    }
  }
  __syncthreads();
  unsigned short* dst = out + (size_t)e * R * C;
  int tx = tid & 7, ty = tid >> 3;
#pragma unroll
  for (int i = 0; i < 2; ++i) {
    int cc = ty + i * 32;
    unsigned short a0 = tile[tx * 8 + 0][cc], a1 = tile[tx * 8 + 1][cc];
    unsigned short a2 = tile[tx * 8 + 2][cc], a3 = tile[tx * 8 + 3][cc];
    unsigned short a4 = tile[tx * 8 + 4][cc], a5 = tile[tx * 8 + 5][cc];
    unsigned short a6 = tile[tx * 8 + 6][cc], a7 = tile[tx * 8 + 7][cc];
    uint4 v;
    v.x = a0 | ((unsigned)a1 << 16); v.y = a2 | ((unsigned)a3 << 16);
    v.z = a4 | ((unsigned)a5 << 16); v.w = a6 | ((unsigned)a7 << 16);
    *(uint4*)(dst + (size_t)(c0 + cc) * R + r0 + tx * 8) = v;
  }
}

// ------------------------------------------------------ gate/up fused GEMM ---
// act[r][i] = gelu_tanh(xc[rows[r]] . gwT[e][i]) * (xc[rows[r]] . uwT[e][i])
__global__ __launch_bounds__(256, 2) void gemm_gateup(
    const unsigned short* __restrict__ xc,    // [T][HID] bf16
    const unsigned short* __restrict__ gwT,   // [E][INTER][HID] bf16
    const unsigned short* __restrict__ uwT,   // [E][INTER][HID] bf16
    const int* __restrict__ rows, const int* __restrict__ offs,
    unsigned short* __restrict__ act) {
  int nRT = offs[NEXP] >> 7;
  int rowTile = blockIdx.x >> 3;
  if (rowTile >= nRT) return;
  int nt = blockIdx.x & 7;
  int row0 = rowTile << 7;
  int e = 0;
  while (row0 >= offs[e + 1]) ++e;

  __shared__ __align__(16) unsigned short xs[TM * BK];   // [m][k] 16KB
  __shared__ __align__(16) unsigned short gs[TM * BK];   // [n][k] 16KB
  __shared__ __align__(16) unsigned short us2[TM * BK];  // [n][k] 16KB

  int tid = threadIdx.x;
  int wave = tid >> 6, lane = tid & 63;
  int lrow = lane & 15, lquad = lane >> 4;
  int wm = (wave >> 1) << 6, wn = (wave & 1) << 6;

  int srow = tid >> 3;        // 0..31 (row within 32-row staging pass)
  int skk  = (tid & 7) << 3;  // short offset within 64-wide row

  size_t xoff[4], woff[4];
  int ldsb[4];
#pragma unroll
  for (int p = 0; p < 4; ++p) {
    xoff[p] = (size_t)rows[row0 + p * 32 + srow] * HID + skk;
    woff[p] = (size_t)(p * 32 + srow) * HID + skk;
    ldsb[p] = (p * 32 + wave * 8) * BK;   // shorts; wave-uniform
  }
  const unsigned short* gB = gwT + ((size_t)e * INTER + (size_t)nt * TM) * HID;
  const unsigned short* uB = uwT + ((size_t)e * INTER + (size_t)nt * TM) * HID;

  f32x4 accg[4][4] = {};
  f32x4 accu[4][4] = {};

  for (int k0 = 0; k0 < HID; k0 += BK) {
#pragma unroll
    for (int p = 0; p < 4; ++p) {
      glds16(xc + xoff[p] + k0, xs + ldsb[p]);
      glds16(gB + woff[p] + k0, gs + ldsb[p]);
      glds16(uB + woff[p] + k0, us2 + ldsb[p]);
    }
    __syncthreads();
#pragma unroll
    for (int ks = 0; ks < BK; ks += 32) {
      bf16x8 bg[4], bu[4];
#pragma unroll
      for (int j = 0; j < 4; ++j) {
        int n = wn + j * 16 + lrow;
        bg[j] = *(const bf16x8*)(gs + n * BK + ks + lquad * 8);
        bu[j] = *(const bf16x8*)(us2 + n * BK + ks + lquad * 8);
      }
#pragma unroll
      for (int i = 0; i < 4; ++i) {
        bf16x8 af = *(const bf16x8*)(xs + (wm + i * 16 + lrow) * BK + ks + lquad * 8);
#pragma unroll
        for (int j = 0; j < 4; ++j) {
          accg[i][j] = __builtin_amdgcn_mfma_f32_16x16x32_bf16(af, bg[j], accg[i][j], 0, 0, 0);
          accu[i][j] = __builtin_amdgcn_mfma_f32_16x16x32_bf16(af, bu[j], accu[i][j], 0, 0, 0);
        }
      }
    }
    __syncthreads();
  }

  int n0 = nt * TM;
#pragma unroll
  for (int i = 0; i < 4; ++i) {
#pragma unroll
    for (int r = 0; r < 4; ++r) {
      int m = row0 + wm + i * 16 + lquad * 4 + r;
      size_t base = (size_t)m * INTER + n0 + wn;
#pragma unroll
      for (int j = 0; j < 4; ++j) {
        float g = accg[i][j][r], u = accu[i][j][r];
        // 0.5*g*(1+tanh(y))*u == g*u*sigmoid(2y), y=0.79788456*(g+0.044715 g^3)
        float z = 1.5957691f * (g + 0.044715f * g * g * g);
        float a = g * u / (1.f + __expf(-z));
        act[base + j * 16 + lrow] = f2bf(a);
      }
    }
  }
}

// ------------------------------------------------- down GEMM + scatter-add ---
__global__ __launch_bounds__(256, 3) void gemm_down(
    const unsigned short* __restrict__ act,   // [rows][INTER] bf16
    const unsigned short* __restrict__ dwT,   // [E][HID][INTER] bf16
    const int* __restrict__ rows, const float* __restrict__ wgt,
    const int* __restrict__ offs, void* __restrict__ outv,
    const int* __restrict__ flagp) {
  int nRT = offs[NEXP] >> 7;
  int rowTile = blockIdx.x >> 4;
  if (rowTile >= nRT) return;
  int flag = *flagp;
  int nt = blockIdx.x & 15;
  int row0 = rowTile << 7;
  int e = 0;
  while (row0 >= offs[e + 1]) ++e;

  __shared__ __align__(16) unsigned short as_[TM * BK];  // 16KB
  __shared__ __align__(16) unsigned short bs[TM * BK];   // 16KB

  int tid = threadIdx.x;
  int wave = tid >> 6, lane = tid & 63;
  int lrow = lane & 15, lquad = lane >> 4;
  int wm = (wave >> 1) << 6, wn = (wave & 1) << 6;

  int srow = tid >> 3;
  int skk  = (tid & 7) << 3;

  size_t aoff[4], woff[4];
  int ldsb[4];
#pragma unroll
  for (int p = 0; p < 4; ++p) {
    aoff[p] = (size_t)(row0 + p * 32 + srow) * INTER + skk;
    woff[p] = (size_t)(p * 32 + srow) * INTER + skk;
    ldsb[p] = (p * 32 + wave * 8) * BK;
  }
  const unsigned short* dB = dwT + ((size_t)e * HID + (size_t)nt * TM) * INTER;

  f32x4 acc[4][4] = {};

  for (int k0 = 0; k0 < INTER; k0 += BK) {
#pragma unroll
    for (int p = 0; p < 4; ++p) {
      glds16(act + aoff[p] + k0, as_ + ldsb[p]);
      glds16(dB + woff[p] + k0, bs + ldsb[p]);
    }
    __syncthreads();
#pragma unroll
    for (int ks = 0; ks < BK; ks += 32) {
      bf16x8 bf[4];
#pragma unroll
      for (int j = 0; j < 4; ++j)
        bf[j] = *(const bf16x8*)(bs + (wn + j * 16 + lrow) * BK + ks + lquad * 8);
#pragma unroll
      for (int i = 0; i < 4; ++i) {
        bf16x8 af = *(const bf16x8*)(as_ + (wm + i * 16 + lrow) * BK + ks + lquad * 8);
#pragma unroll
        for (int j = 0; j < 4; ++j)
          acc[i][j] = __builtin_amdgcn_mfma_f32_16x16x32_bf16(af, bf[j], acc[i][j], 0, 0, 0);
      }
    }
    __syncthreads();
  }

  int n0 = nt * TM;
#pragma unroll
  for (int i = 0; i < 4; ++i) {
#pragma unroll
    for (int r = 0; r < 4; ++r) {
      int mi = row0 + wm + i * 16 + lquad * 4 + r;
      float w = wgt[mi];
      int token = rows[mi];
      size_t base = (size_t)token * HID + n0 + wn;
      if (flag) {
        // bf16 output: pack (even,odd) column pair, CAS accumulate
#pragma unroll
        for (int j = 0; j < 4; ++j) {
          float v = acc[i][j][r] * w;
          float o = __shfl_xor(v, 1);   // partner column (col^1)
          if (((lrow & 1) == 0) && w != 0.f) {
            unsigned* p = (unsigned*)((unsigned short*)outv + base + j * 16 + lrow);
            unsigned old = __atomic_load_n(p, __ATOMIC_RELAXED), assumed;
            do {
              assumed = old;
              float flo = bf2f((unsigned short)(assumed & 0xffffu));
              float fhi = bf2f((unsigned short)(assumed >> 16));
              unsigned nw = (unsigned)f2bf(flo + v) | ((unsigned)f2bf(fhi + o) << 16);
              old = atomicCAS(p, assumed, nw);
            } while (old != assumed);
          }
        }
      } else {
        // fp32 output: one atomicAdd per lane-column
        if (w != 0.f) {
          float* outf = (float*)outv;
#pragma unroll
          for (int j = 0; j < 4; ++j)
            atomicAdd(outf + base + j * 16 + lrow, acc[i][j][r] * w);
        }
      }
    }
  }
}

// ------------------------------------------------------------------ launch ---
extern "C" void kernel_launch(void* const* d_in, const int* in_sizes, int n_in,
                              void* d_out, int out_size, void* d_ws, size_t ws_size,
                              hipStream_t stream) {
  (void)in_sizes; (void)n_in; (void)out_size; (void)ws_size;
  const void* x   = d_in[0];
  const int* sel  = (const int*)d_in[1];
  const void* rw  = d_in[2];
  const void* gw  = d_in[3];
  const void* uw  = d_in[4];
  const void* dw  = d_in[5];

  char* ws = (char*)d_ws;
  int* offs  = (int*)ws;                     // ints 0..8
  int* flagp = (int*)(ws + 64);              // dtype flag
  int* rows  = (int*)(ws + 256);             // 17408 ints
  float* wgt = (float*)(ws + 256 + MAX_ROWS * 4);
  unsigned short* gwT = (unsigned short*)(ws + 256 + MAX_ROWS * 8);
  unsigned short* uwT = gwT + (size_t)NEXP * HID * INTER;
  unsigned short* dwT = uwT + (size_t)NEXP * HID * INTER;
  unsigned short* xc  = dwT + (size_t)NEXP * HID * INTER;  // [T][HID] bf16
  unsigned short* act = xc + (size_t)T_TOK * HID;          // [17408][1024] bf16

  detect_k<<<1, 64, 0, stream>>>((const unsigned*)x, flagp);
  zero_out_k<<<4096, 256, 0, stream>>>((unsigned*)d_out, flagp);
  routing_k<<<1, 256, 0, stream>>>(sel, rw, rows, wgt, offs, flagp);
  transpose_k<<<dim3(INTER / 64, HID / 64, NEXP), 256, 0, stream>>>(gw, gwT, HID, INTER, flagp);
  transpose_k<<<dim3(INTER / 64, HID / 64, NEXP), 256, 0, stream>>>(uw, uwT, HID, INTER, flagp);
  transpose_k<<<dim3(HID / 64, INTER / 64, NEXP), 256, 0, stream>>>(dw, dwT, INTER, HID, flagp);
  convert_x_k<<<4096, 256, 0, stream>>>(x, xc, flagp);
  gemm_gateup<<<MAX_RT * NT_A, 256, 0, stream>>>(xc, gwT, uwT, rows, offs, act);
  gemm_down<<<MAX_RT * NT_B, 256, 0, stream>>>(act, dwT, rows, wgt, offs, d_out, flagp);
}